// Round 16
// baseline (195.132 us; speedup 1.0000x reference)
//
#include <hip/hip_runtime.h>
#include <stdint.h>
#include <math.h>

#define L_DIM 3
#define B_DIM 64
#define P_DIM 225
#define D_DIM 640
#define R_DIM 1800
#define S_DIM 240
#define M_TOT 14400
#define M_PAD 14592             /* 57*256 */
#define N_PAD 1792              /* 7*256 real cols; refs 1792..1799 via rem path */
#define MT 57
#define NT 7
#define KT 10                   /* 640/64 */
#define NGEMM 1197              /* L_DIM*MT*NT */
#define NREM 675                /* L_DIM*M_TOT/64 */
#define BNSCALE 0.99999500003749981f  /* 1/sqrt(1+1e-5) */

typedef __bf16 bf16x8 __attribute__((ext_vector_type(8)));
typedef float f32x4 __attribute__((ext_vector_type(4)));

__device__ __forceinline__ unsigned short f2bf(float f) {
    union { float f; unsigned u; } v; v.f = f;
    unsigned u = v.u;
    unsigned r = (u + 0x7FFFu + ((u >> 16) & 1u)) >> 16;   // RNE
    return (unsigned short)r;
}

// ---------------------------------------------------------------- K0: convert
__global__ __launch_bounds__(256)
void k_convert(const float* __restrict__ pe, const float* __restrict__ per,
               unsigned short* __restrict__ abf, unsigned short* __restrict__ rbf,
               unsigned short* __restrict__ rbf8, float* __restrict__ rnorm)
{
    const int AROWS = L_DIM * M_PAD;            // 43776
    const int BROWS = L_DIM * N_PAD;            // 5376
    int wid = (blockIdx.x * 256 + threadIdx.x) >> 6;
    int lane = threadIdx.x & 63;
    const ushort4 z4 = {0, 0, 0, 0};
    if (wid < AROWS) {
        int l = wid / M_PAD, r = wid - l * M_PAD;
        unsigned short* dst = abf + (size_t)wid * D_DIM;
        if (r < M_TOT) {
            const float4* src = (const float4*)(pe + ((size_t)l * M_TOT + r) * D_DIM);
            float ss = 0.f;
            #pragma unroll
            for (int it = 0; it < 3; ++it) {
                int idx = it * 64 + lane;
                if (idx < 160) {
                    float4 v = src[idx];
                    ss += v.x * v.x + v.y * v.y + v.z * v.z + v.w * v.w;
                    ushort4 o;
                    o.x = f2bf(v.x); o.y = f2bf(v.y); o.z = f2bf(v.z); o.w = f2bf(v.w);
                    *(ushort4*)(dst + idx * 4) = o;
                }
            }
            #pragma unroll
            for (int m = 32; m; m >>= 1) ss += __shfl_xor(ss, m);
            if (lane == 0) rnorm[l * M_TOT + r] = rsqrtf(ss);
        } else {
            #pragma unroll
            for (int it = 0; it < 3; ++it) {
                int idx = it * 64 + lane;
                if (idx < 160) *(ushort4*)(dst + idx * 4) = z4;
            }
        }
    } else if (wid < AROWS + BROWS) {
        int w2 = wid - AROWS;
        int l = w2 / N_PAD, r = w2 - l * N_PAD;   // r < 1792 always real
        unsigned short* dst = rbf + (size_t)w2 * D_DIM;
        const float4* src = (const float4*)(per + ((size_t)l * R_DIM + r) * D_DIM);
        #pragma unroll
        for (int it = 0; it < 3; ++it) {
            int idx = it * 64 + lane;
            if (idx < 160) {
                float4 v = src[idx];
                ushort4 o;
                o.x = f2bf(v.x); o.y = f2bf(v.y); o.z = f2bf(v.z); o.w = f2bf(v.w);
                *(ushort4*)(dst + idx * 4) = o;
            }
        }
    } else {
        int w3 = wid - AROWS - BROWS;             // 0..47
        int l = w3 >> 4, r = w3 & 15;
        unsigned short* dst = rbf8 + (size_t)(l * 16 + r) * D_DIM;
        if (r < 8) {
            const float4* src = (const float4*)(per + ((size_t)l * R_DIM + 1792 + r) * D_DIM);
            #pragma unroll
            for (int it = 0; it < 3; ++it) {
                int idx = it * 64 + lane;
                if (idx < 160) {
                    float4 v = src[idx];
                    ushort4 o;
                    o.x = f2bf(v.x); o.y = f2bf(v.y); o.z = f2bf(v.z); o.w = f2bf(v.w);
                    *(ushort4*)(dst + idx * 4) = o;
                }
            }
        } else {
            #pragma unroll
            for (int it = 0; it < 3; ++it) {
                int idx = it * 64 + lane;
                if (idx < 160) *(ushort4*)(dst + idx * 4) = z4;
            }
        }
    }
}

// ------------- K1: 256^2 4-phase bf16 GEMM + fused rowmax, with fused rem tail
// (Round-6 proven schedule; bids >= NGEMM handle refs 1792..1799 -> rmax8.)
#define MFMA(A, B, C) __builtin_amdgcn_mfma_f32_16x16x32_bf16((A), (B), (C), 0, 0, 0)
#define GLL(SRC, DSTOFF)                                                     \
    __builtin_amdgcn_global_load_lds(                                        \
        (const __attribute__((address_space(1))) void*)(SRC),               \
        (__attribute__((address_space(3))) void*)(lds + (DSTOFF)), 16, 0, 0)

#define PHASE_TAIL(NJB, STG0, STG1, VMSTR)                                   \
    {                                                                        \
        bf16x8 b00 = *(const bf16x8*)(lds + bB + (brow0 + (NJB) * 16) * 64 + sw0);     \
        bf16x8 b01 = *(const bf16x8*)(lds + bB + (brow0 + (NJB) * 16) * 64 + sw1);     \
        bf16x8 b10 = *(const bf16x8*)(lds + bB + (brow0 + (NJB + 1) * 16) * 64 + sw0); \
        bf16x8 b11 = *(const bf16x8*)(lds + bB + (brow0 + (NJB + 1) * 16) * 64 + sw1); \
        STG0; STG1;                                                          \
        asm volatile("s_waitcnt " VMSTR ::: "memory");                       \
        __builtin_amdgcn_s_barrier();                                        \
        __builtin_amdgcn_s_setprio(1);                                       \
        _Pragma("unroll")                                                    \
        for (int mi = 0; mi < 4; ++mi) {                                     \
            acc[mi][NJB]     = MFMA(a[mi][0], b00, acc[mi][NJB]);            \
            acc[mi][NJB]     = MFMA(a[mi][1], b01, acc[mi][NJB]);            \
            acc[mi][NJB + 1] = MFMA(a[mi][0], b10, acc[mi][NJB + 1]);        \
            acc[mi][NJB + 1] = MFMA(a[mi][1], b11, acc[mi][NJB + 1]);        \
        }                                                                    \
        __builtin_amdgcn_s_setprio(0);                                       \
    }

__global__ __launch_bounds__(512, 2)
void k_gemm_max(const unsigned short* __restrict__ abf,
                const unsigned short* __restrict__ rbf,
                const unsigned short* __restrict__ rbf8,
                float* __restrict__ pmax, float* __restrict__ rmax8)
{
    __shared__ unsigned short lds[65536];   // A: [0,32768) 2 bufs; B: [32768,65536)
    __shared__ float red[2][256];

    int bid = blockIdx.x;
    int tid = threadIdx.x;

    if (bid >= NGEMM) {
        // ---- rem path: refs 1792..1799, 64 A-rows per block ----
        int rb2 = bid - NGEMM;                 // 0..674
        int rflat0 = rb2 * 64;
        int l = rflat0 / M_TOT;                // blocks never cross l (14400%64==0)
        // stage this l's 16 ref rows (8 real + 8 zero), 20KB, all 512 threads
        const unsigned* src = (const unsigned*)(rbf8 + (size_t)l * 16 * D_DIM);
        unsigned* dstl = (unsigned*)lds;
        #pragma unroll
        for (int i = 0; i < 10; ++i) dstl[i * 512 + tid] = src[i * 512 + tid];
        __syncthreads();

        int w = (tid >> 6) & 3;                // waves 4-7 mirror 0-3 (benign dup)
        int lane = tid & 63;
        int lane15 = lane & 15, lg = lane >> 4;
        int rl = (rflat0 - l * M_TOT) + w * 16;

        const unsigned short* arow = abf + (size_t)(l * M_PAD + rl + lane15) * D_DIM;
        const unsigned short* brow = lds + (size_t)lane15 * D_DIM;

        f32x4 acc1 = f32x4{0.f, 0.f, 0.f, 0.f};
        for (int kk = 0; kk < D_DIM; kk += 32) {
            bf16x8 aa = *(const bf16x8*)(arow + kk + lg * 8);
            bf16x8 bb = *(const bf16x8*)(brow + kk + lg * 8);
            acc1 = MFMA(aa, bb, acc1);
        }
        // C/D: col = lane15 (ref idx; >=8 zero rows -> mask), row = lg*4+reg
        float t[4];
        #pragma unroll
        for (int r = 0; r < 4; ++r)
            t[r] = (lane15 < 8) ? acc1[r] : -__builtin_inff();
        #pragma unroll
        for (int m = 1; m <= 8; m <<= 1) {
            #pragma unroll
            for (int r = 0; r < 4; ++r) t[r] = fmaxf(t[r], __shfl_xor(t[r], m));
        }
        if (lane15 == 0) {
            #pragma unroll
            for (int r = 0; r < 4; ++r)
                rmax8[(size_t)l * M_TOT + rl + lg * 4 + r] = t[r];
        }
        return;
    }

    // ---- gemm path (R6 proven, bids 0..1196) ----
    // bijective XCD-chunked swizzle: 1197 = 5*150 + 3*149
    int xcd = bid & 7, idx = bid >> 3;
    int v = (xcd < 5 ? xcd * 150 : 750 + (xcd - 5) * 149) + idx;
    int l = v / (MT * NT);
    int rem = v - l * (MT * NT);
    int mt = rem / NT;
    int nt = rem - mt * NT;

    int wid = tid >> 6, lane = tid & 63;
    int wm = wid >> 1;                      // 0..3 -> rows wm*64
    int wn = wid & 1;                       // 0..1 -> cols wn*128
    int lane15 = lane & 15, lg = lane >> 4;
    int sA = lane15 & 7;
    int sw0 = ((lg) ^ sA) << 3;             // ks=0: swizzled col-chunk, in shorts
    int sw1 = ((4 + lg) ^ sA) << 3;         // ks=1
    int arow0 = wm * 64 + lane15;
    int brow0 = wn * 128 + lane15;

    // staging source (pre-swizzled global col so linear LDS dest ends up swizzled)
    int rowc = lane >> 3;
    int scol = ((lane & 7) ^ rowc) << 3;
    const unsigned short* gA = abf + (size_t)(l * M_PAD + mt * 256) * D_DIM;
    const unsigned short* gB = rbf + (size_t)(l * N_PAD + nt * 256) * D_DIM;
    int chA0 = wid, chA1 = 8 + wid, chA2 = 16 + wid, chA3 = 24 + wid;
    int chB0 = (wid < 4) ? (0 + wid) : (12 + wid);
    int chB1 = (wid < 4) ? (4 + wid) : (16 + wid);
    int chB2 = (wid < 4) ? (8 + wid) : (20 + wid);
    int chB3 = (wid < 4) ? (12 + wid) : (24 + wid);
    const unsigned short* pA0 = gA + (size_t)(chA0 * 8 + rowc) * D_DIM + scol;
    const unsigned short* pA1 = gA + (size_t)(chA1 * 8 + rowc) * D_DIM + scol;
    const unsigned short* pA2 = gA + (size_t)(chA2 * 8 + rowc) * D_DIM + scol;
    const unsigned short* pA3 = gA + (size_t)(chA3 * 8 + rowc) * D_DIM + scol;
    const unsigned short* pB0 = gB + (size_t)(chB0 * 8 + rowc) * D_DIM + scol;
    const unsigned short* pB1 = gB + (size_t)(chB1 * 8 + rowc) * D_DIM + scol;
    const unsigned short* pB2 = gB + (size_t)(chB2 * 8 + rowc) * D_DIM + scol;
    const unsigned short* pB3 = gB + (size_t)(chB3 * 8 + rowc) * D_DIM + scol;

    f32x4 acc[4][8];
    #pragma unroll
    for (int mi = 0; mi < 4; ++mi)
        #pragma unroll
        for (int nj = 0; nj < 8; ++nj)
            acc[mi][nj] = f32x4{0.f, 0.f, 0.f, 0.f};

    // prologue: stage K-tile 0 into buf0; need A0..A3 + Bq0 before phase 0
    GLL(pA0, chA0 * 512); GLL(pA1, chA1 * 512);
    GLL(pA2, chA2 * 512); GLL(pA3, chA3 * 512);
    GLL(pB0, 32768 + chB0 * 512); GLL(pB1, 32768 + chB1 * 512);
    GLL(pB2, 32768 + chB2 * 512); GLL(pB3, 32768 + chB3 * 512);
    asm volatile("s_waitcnt vmcnt(3)" ::: "memory");
    __builtin_amdgcn_s_barrier();

    int buf = 0;
    for (int kt = 0; kt < KT; ++kt) {
        int ob = buf ^ 1;
        int aB = buf * 16384;
        int bB = 32768 + buf * 16384;
        int oaB = ob * 16384;
        int obB = 32768 + ob * 16384;
        int koff = (kt + 1 < KT ? kt + 1 : KT - 1) * 64;   // kt=9 restages (dummy)

        // phase 0: read A-all + B quadrant 0; stage A0',A1'
        bf16x8 a[4][2];
        #pragma unroll
        for (int mi = 0; mi < 4; ++mi) {
            a[mi][0] = *(const bf16x8*)(lds + aB + (arow0 + mi * 16) * 64 + sw0);
            a[mi][1] = *(const bf16x8*)(lds + aB + (arow0 + mi * 16) * 64 + sw1);
        }
        PHASE_TAIL(0, GLL(pA0 + koff, oaB + chA0 * 512),
                      GLL(pA1 + koff, oaB + chA1 * 512), "vmcnt(4)")
        // phase 1: B quadrant 1; stage A2',A3'
        PHASE_TAIL(2, GLL(pA2 + koff, oaB + chA2 * 512),
                      GLL(pA3 + koff, oaB + chA3 * 512), "vmcnt(5)")
        // phase 2: B quadrant 2; stage B0',B1'
        PHASE_TAIL(4, GLL(pB0 + koff, obB + chB0 * 512),
                      GLL(pB1 + koff, obB + chB1 * 512), "vmcnt(6)")
        // phase 3: B quadrant 3; stage B2',B3'
        PHASE_TAIL(6, GLL(pB2 + koff, obB + chB2 * 512),
                      GLL(pB3 + koff, obB + chB3 * 512), "vmcnt(3)")
        buf = ob;
    }

    __syncthreads();

    // fused epilogue: rowmax over the block's 256 cols (all real).
    // C/D layout: col = lane&15, row = (lane>>4)*4 + reg  [m89-verified]
    #pragma unroll
    for (int mi = 0; mi < 4; ++mi) {
        float t[4] = {-__builtin_inff(), -__builtin_inff(),
                      -__builtin_inff(), -__builtin_inff()};
        #pragma unroll
        for (int nj = 0; nj < 8; ++nj) {
            #pragma unroll
            for (int r = 0; r < 4; ++r) t[r] = fmaxf(t[r], acc[mi][nj][r]);
        }
        #pragma unroll
        for (int m = 1; m <= 8; m <<= 1) {
            #pragma unroll
            for (int r = 0; r < 4; ++r) t[r] = fmaxf(t[r], __shfl_xor(t[r], m));
        }
        if (lane15 == 0) {
            int rb = wm * 64 + mi * 16 + lg * 4;
            #pragma unroll
            for (int r = 0; r < 4; ++r) red[wn][rb + r] = t[r];
        }
    }
    __syncthreads();
    if (tid < 256) {
        float vmx = fmaxf(red[0][tid], red[1][tid]);
        pmax[((size_t)l * NT + nt) * M_PAD + mt * 256 + tid] = vmx;
    }
}

// --------------------- K3: small net + fused combine (512 thr)
__device__ __forceinline__ float block_sum8(float v, volatile float* scratch) {
    #pragma unroll
    for (int m = 32; m; m >>= 1) v += __shfl_xor(v, m);
    int w = threadIdx.x >> 6;
    __syncthreads();
    if ((threadIdx.x & 63) == 0) scratch[w] = v;
    __syncthreads();
    float r = 0.f;
    #pragma unroll
    for (int i = 0; i < 8; ++i) r += scratch[i];
    return r;
}
__device__ __forceinline__ float block_max8(float v, volatile float* scratch) {
    #pragma unroll
    for (int m = 32; m; m >>= 1) v = fmaxf(v, __shfl_xor(v, m));
    int w = threadIdx.x >> 6;
    __syncthreads();
    if ((threadIdx.x & 63) == 0) scratch[w] = v;
    __syncthreads();
    float r = scratch[0];
    #pragma unroll
    for (int i = 1; i < 8; ++i) r = fmaxf(r, scratch[i]);
    return r;
}

__global__ __launch_bounds__(512)
void k_small(const float* __restrict__ ie, const float* __restrict__ te,
             const float* __restrict__ ier,
             const float* __restrict__ a_w1, const float* __restrict__ a_w2,
             const float* __restrict__ r_w1, const float* __restrict__ r_b1,
             const float* __restrict__ r_g2, const float* __restrict__ r_be2,
             const float* __restrict__ r_w2, const float* __restrict__ r_b2,
             const float* __restrict__ r_g3, const float* __restrict__ r_be3,
             const float* __restrict__ r_w3, const float* __restrict__ r_b3,
             const float* __restrict__ h_w1, const float* __restrict__ h_b1,
             const float* __restrict__ h_g2, const float* __restrict__ h_be2,
             const float* __restrict__ h_w2, const float* __restrict__ h_b2,
             const float* __restrict__ h_g3, const float* __restrict__ h_be3,
             const float* __restrict__ h_w3, const float* __restrict__ h_b3,
             const float* __restrict__ pmax, const float* __restrict__ rmax8,
             const float* __restrict__ rnorm,
             float* __restrict__ heat, float* __restrict__ out_score)
{
    int b = blockIdx.x, tid = threadIdx.x;
    __shared__ float x[D_DIM];
    __shared__ float h1[160];
    __shared__ float dif[D_DIM];
    __shared__ float z1[128];
    __shared__ float z2[64];
    __shared__ float hol[P_DIM];
    __shared__ float rcp[P_DIM];
    __shared__ float scratch[8];

    for (int i = tid; i < D_DIM; i += 512) x[i] = ie[b * D_DIM + i];
    __syncthreads();

    float ss = 0.f, d0 = 0.f, d1 = 0.f;
    for (int i = tid; i < D_DIM; i += 512) {
        float v = x[i];
        ss += v * v;
        d0 += v * te[i];
        d1 += v * te[D_DIM + i];
    }
    float ssum = block_sum8(ss, scratch);
    float dd0 = block_sum8(d0, scratch);
    float dd1 = block_sum8(d1, scratch);
    float tscore = 1.f / (1.f + expf(100.f * rsqrtf(ssum) * (dd0 - dd1)));

    for (int o = tid; o < 160; o += 512) {
        const float* w = a_w1 + (size_t)o * D_DIM;
        float s0 = 0, s1 = 0, s2 = 0, s3 = 0;
        for (int d = 0; d < D_DIM; d += 4) {
            s0 += x[d] * w[d]; s1 += x[d + 1] * w[d + 1];
            s2 += x[d + 2] * w[d + 2]; s3 += x[d + 3] * w[d + 3];
        }
        h1[o] = fmaxf((s0 + s1) + (s2 + s3), 0.f);
    }
    __syncthreads();
    for (int d = tid; d < D_DIM; d += 512) {
        const float* w = a_w2 + (size_t)d * 160;
        float s0 = 0, s1 = 0, s2 = 0, s3 = 0;
        for (int o = 0; o < 160; o += 4) {
            s0 += h1[o] * w[o]; s1 += h1[o + 1] * w[o + 1];
            s2 += h1[o + 2] * w[o + 2]; s3 += h1[o + 3] * w[o + 3];
        }
        dif[d] = ier[d] - fmaxf((s0 + s1) + (s2 + s3), 0.f);
    }
    __syncthreads();

    for (int o = tid; o < 128; o += 512) {
        const float* w = r_w1 + (size_t)o * D_DIM;
        float s0 = 0, s1 = 0, s2 = 0, s3 = 0;
        for (int d = 0; d < D_DIM; d += 4) {
            s0 += dif[d] * w[d]; s1 += dif[d + 1] * w[d + 1];
            s2 += dif[d + 2] * w[d + 2]; s3 += dif[d + 3] * w[d + 3];
        }
        float s = (s0 + s1) + (s2 + s3) + r_b1[o];
        z1[o] = fmaxf(s, 0.f) * (r_g2[o] * BNSCALE) + r_be2[o];
    }
    __syncthreads();
    for (int o = tid; o < 64; o += 512) {
        const float* w = r_w2 + (size_t)o * 128;
        float s = r_b2[o];
        for (int d = 0; d < 128; ++d) s += z1[d] * w[d];
        z2[o] = fmaxf(s, 0.f) * (r_g3[o] * BNSCALE) + r_be3[o];
    }
    __syncthreads();
    float sp = (tid < 64) ? z2[tid] * r_w3[tid] : 0.f;
    float irs = 1.f / (1.f + expf(-(block_sum8(sp, scratch) + r_b3[0])));

    float fgp = -__builtin_inff();
    float base = tscore + irs;
    for (int p = tid; p < P_DIM; p += 512) {
        int r = b * P_DIM + p;
        float s = 0.f;
        #pragma unroll
        for (int l = 0; l < L_DIM; ++l) {
            float m = rmax8[(size_t)l * M_TOT + r];
            #pragma unroll
            for (int t = 0; t < NT; ++t)
                m = fmaxf(m, pmax[((size_t)l * NT + t) * M_PAD + r]);
            s += m * rnorm[l * M_TOT + r];
        }
        float pv = (3.0f - s) / 6.0f;
        fgp = fmaxf(fgp, pv);
        float h = base + pv;
        hol[p] = h;
        rcp[p] = 1.f / h;
    }
    float fg = block_max8(fgp, scratch);

    for (int o = tid; o < 128; o += 512) {
        const float* w = h_w1 + (size_t)o * P_DIM;
        float s = h_b1[o];
        for (int d = 0; d < P_DIM; ++d) s += hol[d] * w[d];
        z1[o] = fmaxf(s, 0.f) * (h_g2[o] * BNSCALE) + h_be2[o];
    }
    __syncthreads();
    for (int o = tid; o < 64; o += 512) {
        const float* w = h_w2 + (size_t)o * 128;
        float s = h_b2[o];
        for (int d = 0; d < 128; ++d) s += z1[d] * w[d];
        z2[o] = fmaxf(s, 0.f) * (h_g3[o] * BNSCALE) + h_be3[o];
    }
    __syncthreads();
    float sp2 = (tid < 64) ? z2[tid] * h_w3[tid] : 0.f;
    float hl_in = block_sum8(sp2, scratch) + h_b3[0];
    if (tid == 0) {
        float hl = 1.f / (1.f + expf(-hl_in));
        out_score[b] = (hl + fg) * 0.5f;
    }

    if (tid < 256) {
        int r = tid >> 4, c = tid & 15;
        float s = 0.f, cnt = 0.f;
        #pragma unroll
        for (int di = -1; di <= 0; ++di) {
            int i = r + di;
            if (i < 0 || i > 14) continue;
            #pragma unroll
            for (int dj = -1; dj <= 0; ++dj) {
                int j = c + dj;
                if (j < 0 || j > 14) continue;
                s += rcp[i * 15 + j];
                cnt += 1.f;
            }
        }
        heat[b * 256 + tid] = cnt / s;
    }
}

// ------------------------------------------------------------- K4: resize
__global__ __launch_bounds__(256)
void k_resize(const float* __restrict__ heat, float* __restrict__ outh)
{
    int b = blockIdx.x >> 3, sub = blockIdx.x & 7;
    __shared__ float h[256];
    if (threadIdx.x < 256) h[threadIdx.x] = heat[b * 256 + threadIdx.x];
    __syncthreads();
    int base = sub * 30 * S_DIM;
    for (int q = threadIdx.x; q < 30 * S_DIM; q += 256) {
        int px = base + q;
        int y = px / S_DIM, xc = px - y * S_DIM;
        float sy = fminf(fmaxf((y - 7) * (1.0f / 15.0f), 0.f), 15.f);
        float sx = fminf(fmaxf((xc - 7) * (1.0f / 15.0f), 0.f), 15.f);
        int y0 = (int)sy, x0 = (int)sx;
        int y1 = min(y0 + 1, 15), x1 = min(x0 + 1, 15);
        float fy = sy - (float)y0, fx = sx - (float)x0;
        float v00 = h[y0 * 16 + x0], v01 = h[y0 * 16 + x1];
        float v10 = h[y1 * 16 + x0], v11 = h[y1 * 16 + x1];
        float v = (1.f - fy) * ((1.f - fx) * v00 + fx * v01)
                + fy * ((1.f - fx) * v10 + fx * v11);
        outh[(size_t)b * (S_DIM * S_DIM) + px] = v;
    }
}

// ---------------------------------------------------------------- launcher
extern "C" void kernel_launch(void* const* d_in, const int* in_sizes, int n_in,
                              void* d_out, int out_size, void* d_ws, size_t ws_size,
                              hipStream_t stream)
{
    (void)in_sizes; (void)n_in; (void)out_size; (void)ws_size;
    const float* image_embeds = (const float*)d_in[1];
    const float* patch_embeds = (const float*)d_in[2];
    const float* text_embeds  = (const float*)d_in[3];
    const float* ier          = (const float*)d_in[4];
    const float* per          = (const float*)d_in[5];
    const float* a_w1 = (const float*)d_in[6];
    const float* a_w2 = (const float*)d_in[7];
    const float* r_w1 = (const float*)d_in[8];
    const float* r_b1 = (const float*)d_in[9];
    const float* r_g2 = (const float*)d_in[10];
    const float* r_be2 = (const float*)d_in[11];
    const float* r_w2 = (const float*)d_in[12];
    const float* r_b2 = (const float*)d_in[13];
    const float* r_g3 = (const float*)d_in[14];
    const float* r_be3 = (const float*)d_in[15];
    const float* r_w3 = (const float*)d_in[16];
    const float* r_b3 = (const float*)d_in[17];
    const float* h_w1 = (const float*)d_in[18];
    const float* h_b1 = (const float*)d_in[19];
    const float* h_g2 = (const float*)d_in[20];
    const float* h_be2 = (const float*)d_in[21];
    const float* h_w2 = (const float*)d_in[22];
    const float* h_b2 = (const float*)d_in[23];
    const float* h_g3 = (const float*)d_in[24];
    const float* h_be3 = (const float*)d_in[25];
    const float* h_w3 = (const float*)d_in[26];
    const float* h_b3 = (const float*)d_in[27];

    char* ws = (char*)d_ws;
    size_t off = 0;
    auto take = [&](size_t bytes) -> void* {
        void* p = ws + off;
        off += (bytes + 255) & ~(size_t)255;
        return p;
    };
    float* rnorm = (float*)take((size_t)L_DIM * M_TOT * 4);            // 173 KB
    float* pmax  = (float*)take((size_t)L_DIM * NT * M_PAD * 4);       // 1.2 MB
    float* rmax8 = (float*)take((size_t)L_DIM * M_TOT * 4);            // 173 KB
    float* heat  = (float*)take((size_t)B_DIM * 256 * 4);              // 64 KB
    unsigned short* abf  = (unsigned short*)take((size_t)L_DIM * M_PAD * D_DIM * 2); // 56.0 MB
    unsigned short* rbf  = (unsigned short*)take((size_t)L_DIM * N_PAD * D_DIM * 2); //  6.9 MB
    unsigned short* rbf8 = (unsigned short*)take((size_t)L_DIM * 16 * D_DIM * 2);    //  61 KB

    float* out_f = (float*)d_out;  // [64] final_score || [64*240*240] hmap, f32

    k_convert<<<dim3((L_DIM * M_PAD + L_DIM * N_PAD + L_DIM * 16) / 4), dim3(256), 0, stream>>>(
        patch_embeds, per, abf, rbf, rbf8, rnorm);
    k_gemm_max<<<dim3(NGEMM + NREM), dim3(512), 0, stream>>>(abf, rbf, rbf8, pmax, rmax8);
    k_small<<<dim3(B_DIM), dim3(512), 0, stream>>>(image_embeds, text_embeds, ier,
        a_w1, a_w2, r_w1, r_b1, r_g2, r_be2, r_w2, r_b2, r_g3, r_be3, r_w3, r_b3,
        h_w1, h_b1, h_g2, h_be2, h_w2, h_b2, h_g3, h_be3, h_w3, h_b3,
        pmax, rmax8, rnorm, heat, out_f);
    k_resize<<<dim3(B_DIM * 8), dim3(256), 0, stream>>>(heat, out_f + B_DIM);
}

// Round 17
// 192.700 us; speedup vs baseline: 1.0126x; 1.0126x over previous
//
#include <hip/hip_runtime.h>
#include <stdint.h>
#include <math.h>

#define L_DIM 3
#define B_DIM 64
#define P_DIM 225
#define D_DIM 640
#define R_DIM 1800
#define S_DIM 240
#define M_TOT 14400
#define M_PAD 14592             /* 57*256 */
#define N_PAD 1792              /* 7*256 real cols; refs 1792..1799 via k_rem */
#define MT 57
#define NT 7
#define KT 10                   /* 640/64 */
#define LPAD 648                /* k_rem LDS row stride (shorts): 2-way banks */
#define BNSCALE 0.99999500003749981f  /* 1/sqrt(1+1e-5) */

typedef __bf16 bf16x8 __attribute__((ext_vector_type(8)));
typedef float f32x4 __attribute__((ext_vector_type(4)));

__device__ __forceinline__ unsigned short f2bf(float f) {
    union { float f; unsigned u; } v; v.f = f;
    unsigned u = v.u;
    unsigned r = (u + 0x7FFFu + ((u >> 16) & 1u)) >> 16;   // RNE
    return (unsigned short)r;
}

// ---------------------------------------------------------------- K0: convert
__global__ __launch_bounds__(256)
void k_convert(const float* __restrict__ pe, const float* __restrict__ per,
               unsigned short* __restrict__ abf, unsigned short* __restrict__ rbf,
               unsigned short* __restrict__ rbf8, float* __restrict__ rnorm)
{
    const int AROWS = L_DIM * M_PAD;            // 43776
    const int BROWS = L_DIM * N_PAD;            // 5376
    int wid = (blockIdx.x * 256 + threadIdx.x) >> 6;
    int lane = threadIdx.x & 63;
    const ushort4 z4 = {0, 0, 0, 0};
    if (wid < AROWS) {
        int l = wid / M_PAD, r = wid - l * M_PAD;
        unsigned short* dst = abf + (size_t)wid * D_DIM;
        if (r < M_TOT) {
            const float4* src = (const float4*)(pe + ((size_t)l * M_TOT + r) * D_DIM);
            float ss = 0.f;
            #pragma unroll
            for (int it = 0; it < 3; ++it) {
                int idx = it * 64 + lane;
                if (idx < 160) {
                    float4 v = src[idx];
                    ss += v.x * v.x + v.y * v.y + v.z * v.z + v.w * v.w;
                    ushort4 o;
                    o.x = f2bf(v.x); o.y = f2bf(v.y); o.z = f2bf(v.z); o.w = f2bf(v.w);
                    *(ushort4*)(dst + idx * 4) = o;
                }
            }
            #pragma unroll
            for (int m = 32; m; m >>= 1) ss += __shfl_xor(ss, m);
            if (lane == 0) rnorm[l * M_TOT + r] = rsqrtf(ss);
        } else {
            #pragma unroll
            for (int it = 0; it < 3; ++it) {
                int idx = it * 64 + lane;
                if (idx < 160) *(ushort4*)(dst + idx * 4) = z4;
            }
        }
    } else if (wid < AROWS + BROWS) {
        int w2 = wid - AROWS;
        int l = w2 / N_PAD, r = w2 - l * N_PAD;   // r < 1792 always real
        unsigned short* dst = rbf + (size_t)w2 * D_DIM;
        const float4* src = (const float4*)(per + ((size_t)l * R_DIM + r) * D_DIM);
        #pragma unroll
        for (int it = 0; it < 3; ++it) {
            int idx = it * 64 + lane;
            if (idx < 160) {
                float4 v = src[idx];
                ushort4 o;
                o.x = f2bf(v.x); o.y = f2bf(v.y); o.z = f2bf(v.z); o.w = f2bf(v.w);
                *(ushort4*)(dst + idx * 4) = o;
            }
        }
    } else {
        int w3 = wid - AROWS - BROWS;             // 0..47
        int l = w3 >> 4, r = w3 & 15;
        unsigned short* dst = rbf8 + (size_t)(l * 16 + r) * D_DIM;
        if (r < 8) {
            const float4* src = (const float4*)(per + ((size_t)l * R_DIM + 1792 + r) * D_DIM);
            #pragma unroll
            for (int it = 0; it < 3; ++it) {
                int idx = it * 64 + lane;
                if (idx < 160) {
                    float4 v = src[idx];
                    ushort4 o;
                    o.x = f2bf(v.x); o.y = f2bf(v.y); o.z = f2bf(v.z); o.w = f2bf(v.w);
                    *(ushort4*)(dst + idx * 4) = o;
                }
            }
        } else {
            #pragma unroll
            for (int it = 0; it < 3; ++it) {
                int idx = it * 64 + lane;
                if (idx < 160) *(ushort4*)(dst + idx * 4) = z4;
            }
        }
    }
}

// ----------------------------------- K1: 256^2 4-phase bf16 GEMM + fused rowmax
// (Round-6 proven schedule; NT=7 so all 1792 cols are real -> no masking.)
#define MFMA(A, B, C) __builtin_amdgcn_mfma_f32_16x16x32_bf16((A), (B), (C), 0, 0, 0)
#define GLL(SRC, DSTOFF)                                                     \
    __builtin_amdgcn_global_load_lds(                                        \
        (const __attribute__((address_space(1))) void*)(SRC),               \
        (__attribute__((address_space(3))) void*)(lds + (DSTOFF)), 16, 0, 0)

#define PHASE_TAIL(NJB, STG0, STG1, VMSTR)                                   \
    {                                                                        \
        bf16x8 b00 = *(const bf16x8*)(lds + bB + (brow0 + (NJB) * 16) * 64 + sw0);     \
        bf16x8 b01 = *(const bf16x8*)(lds + bB + (brow0 + (NJB) * 16) * 64 + sw1);     \
        bf16x8 b10 = *(const bf16x8*)(lds + bB + (brow0 + (NJB + 1) * 16) * 64 + sw0); \
        bf16x8 b11 = *(const bf16x8*)(lds + bB + (brow0 + (NJB + 1) * 16) * 64 + sw1); \
        STG0; STG1;                                                          \
        asm volatile("s_waitcnt " VMSTR ::: "memory");                       \
        __builtin_amdgcn_s_barrier();                                        \
        __builtin_amdgcn_s_setprio(1);                                       \
        _Pragma("unroll")                                                    \
        for (int mi = 0; mi < 4; ++mi) {                                     \
            acc[mi][NJB]     = MFMA(a[mi][0], b00, acc[mi][NJB]);            \
            acc[mi][NJB]     = MFMA(a[mi][1], b01, acc[mi][NJB]);            \
            acc[mi][NJB + 1] = MFMA(a[mi][0], b10, acc[mi][NJB + 1]);        \
            acc[mi][NJB + 1] = MFMA(a[mi][1], b11, acc[mi][NJB + 1]);        \
        }                                                                    \
        __builtin_amdgcn_s_setprio(0);                                       \
    }

__global__ __launch_bounds__(512, 2)
void k_gemm_max(const unsigned short* __restrict__ abf,
                const unsigned short* __restrict__ rbf,
                float* __restrict__ pmax)
{
    __shared__ unsigned short lds[65536];   // A: [0,32768) 2 bufs; B: [32768,65536)
    __shared__ float red[2][256];

    // bijective XCD-chunked swizzle: 1197 = 5*150 + 3*149
    int bid = blockIdx.x;
    int xcd = bid & 7, idx = bid >> 3;
    int v = (xcd < 5 ? xcd * 150 : 750 + (xcd - 5) * 149) + idx;
    int l = v / (MT * NT);
    int rem = v - l * (MT * NT);
    int mt = rem / NT;
    int nt = rem - mt * NT;

    int tid = threadIdx.x;
    int wid = tid >> 6, lane = tid & 63;
    int wm = wid >> 1;                      // 0..3 -> rows wm*64
    int wn = wid & 1;                       // 0..1 -> cols wn*128
    int lane15 = lane & 15, lg = lane >> 4;
    int sA = lane15 & 7;
    int sw0 = ((lg) ^ sA) << 3;             // ks=0: swizzled col-chunk, in shorts
    int sw1 = ((4 + lg) ^ sA) << 3;         // ks=1
    int arow0 = wm * 64 + lane15;
    int brow0 = wn * 128 + lane15;

    // staging source (pre-swizzled global col so linear LDS dest ends up swizzled)
    int rowc = lane >> 3;
    int scol = ((lane & 7) ^ rowc) << 3;
    const unsigned short* gA = abf + (size_t)(l * M_PAD + mt * 256) * D_DIM;
    const unsigned short* gB = rbf + (size_t)(l * N_PAD + nt * 256) * D_DIM;
    int chA0 = wid, chA1 = 8 + wid, chA2 = 16 + wid, chA3 = 24 + wid;
    int chB0 = (wid < 4) ? (0 + wid) : (12 + wid);
    int chB1 = (wid < 4) ? (4 + wid) : (16 + wid);
    int chB2 = (wid < 4) ? (8 + wid) : (20 + wid);
    int chB3 = (wid < 4) ? (12 + wid) : (24 + wid);
    const unsigned short* pA0 = gA + (size_t)(chA0 * 8 + rowc) * D_DIM + scol;
    const unsigned short* pA1 = gA + (size_t)(chA1 * 8 + rowc) * D_DIM + scol;
    const unsigned short* pA2 = gA + (size_t)(chA2 * 8 + rowc) * D_DIM + scol;
    const unsigned short* pA3 = gA + (size_t)(chA3 * 8 + rowc) * D_DIM + scol;
    const unsigned short* pB0 = gB + (size_t)(chB0 * 8 + rowc) * D_DIM + scol;
    const unsigned short* pB1 = gB + (size_t)(chB1 * 8 + rowc) * D_DIM + scol;
    const unsigned short* pB2 = gB + (size_t)(chB2 * 8 + rowc) * D_DIM + scol;
    const unsigned short* pB3 = gB + (size_t)(chB3 * 8 + rowc) * D_DIM + scol;

    f32x4 acc[4][8];
    #pragma unroll
    for (int mi = 0; mi < 4; ++mi)
        #pragma unroll
        for (int nj = 0; nj < 8; ++nj)
            acc[mi][nj] = f32x4{0.f, 0.f, 0.f, 0.f};

    // prologue: stage K-tile 0 into buf0; need A0..A3 + Bq0 before phase 0
    GLL(pA0, chA0 * 512); GLL(pA1, chA1 * 512);
    GLL(pA2, chA2 * 512); GLL(pA3, chA3 * 512);
    GLL(pB0, 32768 + chB0 * 512); GLL(pB1, 32768 + chB1 * 512);
    GLL(pB2, 32768 + chB2 * 512); GLL(pB3, 32768 + chB3 * 512);
    asm volatile("s_waitcnt vmcnt(3)" ::: "memory");
    __builtin_amdgcn_s_barrier();

    int buf = 0;
    for (int kt = 0; kt < KT; ++kt) {
        int ob = buf ^ 1;
        int aB = buf * 16384;
        int bB = 32768 + buf * 16384;
        int oaB = ob * 16384;
        int obB = 32768 + ob * 16384;
        int koff = (kt + 1 < KT ? kt + 1 : KT - 1) * 64;   // kt=9 restages (dummy)

        // phase 0: read A-all + B quadrant 0; stage A0',A1'
        bf16x8 a[4][2];
        #pragma unroll
        for (int mi = 0; mi < 4; ++mi) {
            a[mi][0] = *(const bf16x8*)(lds + aB + (arow0 + mi * 16) * 64 + sw0);
            a[mi][1] = *(const bf16x8*)(lds + aB + (arow0 + mi * 16) * 64 + sw1);
        }
        PHASE_TAIL(0, GLL(pA0 + koff, oaB + chA0 * 512),
                      GLL(pA1 + koff, oaB + chA1 * 512), "vmcnt(4)")
        // phase 1: B quadrant 1; stage A2',A3'
        PHASE_TAIL(2, GLL(pA2 + koff, oaB + chA2 * 512),
                      GLL(pA3 + koff, oaB + chA3 * 512), "vmcnt(5)")
        // phase 2: B quadrant 2; stage B0',B1'
        PHASE_TAIL(4, GLL(pB0 + koff, obB + chB0 * 512),
                      GLL(pB1 + koff, obB + chB1 * 512), "vmcnt(6)")
        // phase 3: B quadrant 3; stage B2',B3'
        PHASE_TAIL(6, GLL(pB2 + koff, obB + chB2 * 512),
                      GLL(pB3 + koff, obB + chB3 * 512), "vmcnt(3)")
        buf = ob;
    }

    __syncthreads();

    // fused epilogue: rowmax over the block's 256 cols (all real).
    // C/D layout: col = lane&15, row = (lane>>4)*4 + reg  [m89-verified]
    #pragma unroll
    for (int mi = 0; mi < 4; ++mi) {
        float t[4] = {-__builtin_inff(), -__builtin_inff(),
                      -__builtin_inff(), -__builtin_inff()};
        #pragma unroll
        for (int nj = 0; nj < 8; ++nj) {
            #pragma unroll
            for (int r = 0; r < 4; ++r) t[r] = fmaxf(t[r], acc[mi][nj][r]);
        }
        #pragma unroll
        for (int m = 1; m <= 8; m <<= 1) {
            #pragma unroll
            for (int r = 0; r < 4; ++r) t[r] = fmaxf(t[r], __shfl_xor(t[r], m));
        }
        if (lane15 == 0) {
            int rb = wm * 64 + mi * 16 + lg * 4;
            #pragma unroll
            for (int r = 0; r < 4; ++r) red[wn][rb + r] = t[r];
        }
    }
    __syncthreads();
    if (tid < 256) {
        float vmx = fmaxf(red[0][tid], red[1][tid]);
        pmax[((size_t)l * NT + nt) * M_PAD + mt * 256 + tid] = vmx;
    }
}

// ------------- K2: remainder refs 1792..1799 -> rmax8[l][row] (MFMA, 16-row tiles)
// LDS rows padded to LPAD shorts: bank = lane15*4 mod 32 -> 2-way (free).
__global__ __launch_bounds__(256)
void k_rem(const unsigned short* __restrict__ abf,
           const unsigned short* __restrict__ rbf8,
           float* __restrict__ rmax8)
{
    __shared__ unsigned short ldsb[16 * LPAD];     // ~20.7KB, one l per block
    int bid = blockIdx.x;                          // 675 blocks, 64 rows each
    int rflat0 = bid * 64;
    int l = rflat0 / M_TOT;                        // blocks never cross l (14400%64==0)
    int tid = threadIdx.x;

    {   // stage this l's 16 ref rows (8 real + 8 zero) into padded LDS
        const unsigned* src = (const unsigned*)(rbf8 + (size_t)l * 16 * D_DIM);
        #pragma unroll
        for (int it = 0; it < 20; ++it) {
            int i = it * 256 + tid;                // 0..5119
            int r = i / 320, c = i - r * 320;
            *(unsigned*)(ldsb + r * LPAD + c * 2) = src[i];
        }
    }
    __syncthreads();

    int w = tid >> 6, lane = tid & 63;
    int lane15 = lane & 15, lg = lane >> 4;
    int rl = (rflat0 - l * M_TOT) + w * 16;        // wave's 16-row base within l

    const unsigned short* arow = abf + (size_t)(l * M_PAD + rl + lane15) * D_DIM;
    const unsigned short* brow = ldsb + (size_t)lane15 * LPAD;

    f32x4 acc = f32x4{0.f, 0.f, 0.f, 0.f};
    for (int kk = 0; kk < D_DIM; kk += 32) {
        bf16x8 a = *(const bf16x8*)(arow + kk + lg * 8);
        bf16x8 b = *(const bf16x8*)(brow + kk + lg * 8);
        acc = MFMA(a, b, acc);
    }

    // C/D: col = lane15 (ref idx; >=8 are zero rows -> mask), row = lg*4+reg
    float t[4];
    #pragma unroll
    for (int r = 0; r < 4; ++r)
        t[r] = (lane15 < 8) ? acc[r] : -__builtin_inff();
    #pragma unroll
    for (int m = 1; m <= 8; m <<= 1) {
        #pragma unroll
        for (int r = 0; r < 4; ++r) t[r] = fmaxf(t[r], __shfl_xor(t[r], m));
    }
    if (lane15 == 0) {
        #pragma unroll
        for (int r = 0; r < 4; ++r)
            rmax8[(size_t)l * M_TOT + rl + lg * 4 + r] = t[r];
    }
}

// --------------------- K3: small net + fused combine (512 thr)
__device__ __forceinline__ float block_sum8(float v, volatile float* scratch) {
    #pragma unroll
    for (int m = 32; m; m >>= 1) v += __shfl_xor(v, m);
    int w = threadIdx.x >> 6;
    __syncthreads();
    if ((threadIdx.x & 63) == 0) scratch[w] = v;
    __syncthreads();
    float r = 0.f;
    #pragma unroll
    for (int i = 0; i < 8; ++i) r += scratch[i];
    return r;
}
__device__ __forceinline__ float block_max8(float v, volatile float* scratch) {
    #pragma unroll
    for (int m = 32; m; m >>= 1) v = fmaxf(v, __shfl_xor(v, m));
    int w = threadIdx.x >> 6;
    __syncthreads();
    if ((threadIdx.x & 63) == 0) scratch[w] = v;
    __syncthreads();
    float r = scratch[0];
    #pragma unroll
    for (int i = 1; i < 8; ++i) r = fmaxf(r, scratch[i]);
    return r;
}

__global__ __launch_bounds__(512)
void k_small(const float* __restrict__ ie, const float* __restrict__ te,
             const float* __restrict__ ier,
             const float* __restrict__ a_w1, const float* __restrict__ a_w2,
             const float* __restrict__ r_w1, const float* __restrict__ r_b1,
             const float* __restrict__ r_g2, const float* __restrict__ r_be2,
             const float* __restrict__ r_w2, const float* __restrict__ r_b2,
             const float* __restrict__ r_g3, const float* __restrict__ r_be3,
             const float* __restrict__ r_w3, const float* __restrict__ r_b3,
             const float* __restrict__ h_w1, const float* __restrict__ h_b1,
             const float* __restrict__ h_g2, const float* __restrict__ h_be2,
             const float* __restrict__ h_w2, const float* __restrict__ h_b2,
             const float* __restrict__ h_g3, const float* __restrict__ h_be3,
             const float* __restrict__ h_w3, const float* __restrict__ h_b3,
             const float* __restrict__ pmax, const float* __restrict__ rmax8,
             const float* __restrict__ rnorm,
             float* __restrict__ heat, float* __restrict__ out_score)
{
    int b = blockIdx.x, tid = threadIdx.x;
    __shared__ float x[D_DIM];
    __shared__ float h1[160];
    __shared__ float dif[D_DIM];
    __shared__ float z1[128];
    __shared__ float z2[64];
    __shared__ float hol[P_DIM];
    __shared__ float rcp[P_DIM];
    __shared__ float scratch[8];

    for (int i = tid; i < D_DIM; i += 512) x[i] = ie[b * D_DIM + i];
    __syncthreads();

    float ss = 0.f, d0 = 0.f, d1 = 0.f;
    for (int i = tid; i < D_DIM; i += 512) {
        float v = x[i];
        ss += v * v;
        d0 += v * te[i];
        d1 += v * te[D_DIM + i];
    }
    float ssum = block_sum8(ss, scratch);
    float dd0 = block_sum8(d0, scratch);
    float dd1 = block_sum8(d1, scratch);
    float tscore = 1.f / (1.f + expf(100.f * rsqrtf(ssum) * (dd0 - dd1)));

    for (int o = tid; o < 160; o += 512) {
        const float* w = a_w1 + (size_t)o * D_DIM;
        float s0 = 0, s1 = 0, s2 = 0, s3 = 0;
        for (int d = 0; d < D_DIM; d += 4) {
            s0 += x[d] * w[d]; s1 += x[d + 1] * w[d + 1];
            s2 += x[d + 2] * w[d + 2]; s3 += x[d + 3] * w[d + 3];
        }
        h1[o] = fmaxf((s0 + s1) + (s2 + s3), 0.f);
    }
    __syncthreads();
    for (int d = tid; d < D_DIM; d += 512) {
        const float* w = a_w2 + (size_t)d * 160;
        float s0 = 0, s1 = 0, s2 = 0, s3 = 0;
        for (int o = 0; o < 160; o += 4) {
            s0 += h1[o] * w[o]; s1 += h1[o + 1] * w[o + 1];
            s2 += h1[o + 2] * w[o + 2]; s3 += h1[o + 3] * w[o + 3];
        }
        dif[d] = ier[d] - fmaxf((s0 + s1) + (s2 + s3), 0.f);
    }
    __syncthreads();

    for (int o = tid; o < 128; o += 512) {
        const float* w = r_w1 + (size_t)o * D_DIM;
        float s0 = 0, s1 = 0, s2 = 0, s3 = 0;
        for (int d = 0; d < D_DIM; d += 4) {
            s0 += dif[d] * w[d]; s1 += dif[d + 1] * w[d + 1];
            s2 += dif[d + 2] * w[d + 2]; s3 += dif[d + 3] * w[d + 3];
        }
        float s = (s0 + s1) + (s2 + s3) + r_b1[o];
        z1[o] = fmaxf(s, 0.f) * (r_g2[o] * BNSCALE) + r_be2[o];
    }
    __syncthreads();
    for (int o = tid; o < 64; o += 512) {
        const float* w = r_w2 + (size_t)o * 128;
        float s = r_b2[o];
        for (int d = 0; d < 128; ++d) s += z1[d] * w[d];
        z2[o] = fmaxf(s, 0.f) * (r_g3[o] * BNSCALE) + r_be3[o];
    }
    __syncthreads();
    float sp = (tid < 64) ? z2[tid] * r_w3[tid] : 0.f;
    float irs = 1.f / (1.f + expf(-(block_sum8(sp, scratch) + r_b3[0])));

    float fgp = -__builtin_inff();
    float base = tscore + irs;
    for (int p = tid; p < P_DIM; p += 512) {
        int r = b * P_DIM + p;
        float s = 0.f;
        #pragma unroll
        for (int l = 0; l < L_DIM; ++l) {
            float m = rmax8[(size_t)l * M_TOT + r];
            #pragma unroll
            for (int t = 0; t < NT; ++t)
                m = fmaxf(m, pmax[((size_t)l * NT + t) * M_PAD + r]);
            s += m * rnorm[l * M_TOT + r];
        }
        float pv = (3.0f - s) / 6.0f;
        fgp = fmaxf(fgp, pv);
        float h = base + pv;
        hol[p] = h;
        rcp[p] = 1.f / h;
    }
    float fg = block_max8(fgp, scratch);

    for (int o = tid; o < 128; o += 512) {
        const float* w = h_w1 + (size_t)o * P_DIM;
        float s = h_b1[o];
        for (int d = 0; d < P_DIM; ++d) s += hol[d] * w[d];
        z1[o] = fmaxf(s, 0.f) * (h_g2[o] * BNSCALE) + h_be2[o];
    }
    __syncthreads();
    for (int o = tid; o < 64; o += 512) {
        const float* w = h_w2 + (size_t)o * 128;
        float s = h_b2[o];
        for (int d = 0; d < 128; ++d) s += z1[d] * w[d];
        z2[o] = fmaxf(s, 0.f) * (h_g3[o] * BNSCALE) + h_be3[o];
    }
    __syncthreads();
    float sp2 = (tid < 64) ? z2[tid] * h_w3[tid] : 0.f;
    float hl_in = block_sum8(sp2, scratch) + h_b3[0];
    if (tid == 0) {
        float hl = 1.f / (1.f + expf(-hl_in));
        out_score[b] = (hl + fg) * 0.5f;
    }

    if (tid < 256) {
        int r = tid >> 4, c = tid & 15;
        float s = 0.f, cnt = 0.f;
        #pragma unroll
        for (int di = -1; di <= 0; ++di) {
            int i = r + di;
            if (i < 0 || i > 14) continue;
            #pragma unroll
            for (int dj = -1; dj <= 0; ++dj) {
                int j = c + dj;
                if (j < 0 || j > 14) continue;
                s += rcp[i * 15 + j];
                cnt += 1.f;
            }
        }
        heat[b * 256 + tid] = cnt / s;
    }
}

// ------------------------------------------------------------- K4: resize
__global__ __launch_bounds__(256)
void k_resize(const float* __restrict__ heat, float* __restrict__ outh)
{
    int b = blockIdx.x >> 3, sub = blockIdx.x & 7;
    __shared__ float h[256];
    if (threadIdx.x < 256) h[threadIdx.x] = heat[b * 256 + threadIdx.x];
    __syncthreads();
    int base = sub * 30 * S_DIM;
    for (int q = threadIdx.x; q < 30 * S_DIM; q += 256) {
        int px = base + q;
        int y = px / S_DIM, xc = px - y * S_DIM;
        float sy = fminf(fmaxf((y - 7) * (1.0f / 15.0f), 0.f), 15.f);
        float sx = fminf(fmaxf((xc - 7) * (1.0f / 15.0f), 0.f), 15.f);
        int y0 = (int)sy, x0 = (int)sx;
        int y1 = min(y0 + 1, 15), x1 = min(x0 + 1, 15);
        float fy = sy - (float)y0, fx = sx - (float)x0;
        float v00 = h[y0 * 16 + x0], v01 = h[y0 * 16 + x1];
        float v10 = h[y1 * 16 + x0], v11 = h[y1 * 16 + x1];
        float v = (1.f - fy) * ((1.f - fx) * v00 + fx * v01)
                + fy * ((1.f - fx) * v10 + fx * v11);
        outh[(size_t)b * (S_DIM * S_DIM) + px] = v;
    }
}

// ---------------------------------------------------------------- launcher
extern "C" void kernel_launch(void* const* d_in, const int* in_sizes, int n_in,
                              void* d_out, int out_size, void* d_ws, size_t ws_size,
                              hipStream_t stream)
{
    (void)in_sizes; (void)n_in; (void)out_size; (void)ws_size;
    const float* image_embeds = (const float*)d_in[1];
    const float* patch_embeds = (const float*)d_in[2];
    const float* text_embeds  = (const float*)d_in[3];
    const float* ier          = (const float*)d_in[4];
    const float* per          = (const float*)d_in[5];
    const float* a_w1 = (const float*)d_in[6];
    const float* a_w2 = (const float*)d_in[7];
    const float* r_w1 = (const float*)d_in[8];
    const float* r_b1 = (const float*)d_in[9];
    const float* r_g2 = (const float*)d_in[10];
    const float* r_be2 = (const float*)d_in[11];
    const float* r_w2 = (const float*)d_in[12];
    const float* r_b2 = (const float*)d_in[13];
    const float* r_g3 = (const float*)d_in[14];
    const float* r_be3 = (const float*)d_in[15];
    const float* r_w3 = (const float*)d_in[16];
    const float* r_b3 = (const float*)d_in[17];
    const float* h_w1 = (const float*)d_in[18];
    const float* h_b1 = (const float*)d_in[19];
    const float* h_g2 = (const float*)d_in[20];
    const float* h_be2 = (const float*)d_in[21];
    const float* h_w2 = (const float*)d_in[22];
    const float* h_b2 = (const float*)d_in[23];
    const float* h_g3 = (const float*)d_in[24];
    const float* h_be3 = (const float*)d_in[25];
    const float* h_w3 = (const float*)d_in[26];
    const float* h_b3 = (const float*)d_in[27];

    char* ws = (char*)d_ws;
    size_t off = 0;
    auto take = [&](size_t bytes) -> void* {
        void* p = ws + off;
        off += (bytes + 255) & ~(size_t)255;
        return p;
    };
    float* rnorm = (float*)take((size_t)L_DIM * M_TOT * 4);            // 173 KB
    float* pmax  = (float*)take((size_t)L_DIM * NT * M_PAD * 4);       // 1.2 MB
    float* rmax8 = (float*)take((size_t)L_DIM * M_TOT * 4);            // 173 KB
    float* heat  = (float*)take((size_t)B_DIM * 256 * 4);              // 64 KB
    unsigned short* abf  = (unsigned short*)take((size_t)L_DIM * M_PAD * D_DIM * 2); // 56.0 MB
    unsigned short* rbf  = (unsigned short*)take((size_t)L_DIM * N_PAD * D_DIM * 2); //  6.9 MB
    unsigned short* rbf8 = (unsigned short*)take((size_t)L_DIM * 16 * D_DIM * 2);    //  61 KB

    float* out_f = (float*)d_out;  // [64] final_score || [64*240*240] hmap, f32

    k_convert<<<dim3((L_DIM * M_PAD + L_DIM * N_PAD + L_DIM * 16) / 4), dim3(256), 0, stream>>>(
        patch_embeds, per, abf, rbf, rbf8, rnorm);
    k_gemm_max<<<dim3(L_DIM * MT * NT), dim3(512), 0, stream>>>(abf, rbf, pmax);
    k_rem<<<dim3(L_DIM * M_TOT / 64), dim3(256), 0, stream>>>(abf, rbf8, rmax8);
    k_small<<<dim3(B_DIM), dim3(512), 0, stream>>>(image_embeds, text_embeds, ier,
        a_w1, a_w2, r_w1, r_b1, r_g2, r_be2, r_w2, r_b2, r_g3, r_be3, r_w3, r_b3,
        h_w1, h_b1, h_g2, h_be2, h_w2, h_b2, h_g3, h_be3, h_w3, h_b3,
        pmax, rmax8, rnorm, heat, out_f);
    k_resize<<<dim3(B_DIM * 8), dim3(256), 0, stream>>>(heat, out_f + B_DIM);
}

// Round 18
// 191.591 us; speedup vs baseline: 1.0185x; 1.0058x over previous
//
#include <hip/hip_runtime.h>
#include <stdint.h>
#include <math.h>

#define L_DIM 3
#define B_DIM 64
#define P_DIM 225
#define D_DIM 640
#define R_DIM 1800
#define S_DIM 240
#define M_TOT 14400
#define M_PAD 14592             /* 57*256 */
#define N_PAD 1792              /* 7*256 real cols; refs 1792..1799 via k_rem */
#define MT 57
#define NT 7
#define KT 10                   /* 640/64 */
#define LPAD 648                /* k_rem LDS row stride (shorts): 2-way banks */
#define BNSCALE 0.99999500003749981f  /* 1/sqrt(1+1e-5) */

typedef __bf16 bf16x8 __attribute__((ext_vector_type(8)));
typedef float f32x4 __attribute__((ext_vector_type(4)));

__device__ __forceinline__ unsigned short f2bf(float f) {
    union { float f; unsigned u; } v; v.f = f;
    unsigned u = v.u;
    unsigned r = (u + 0x7FFFu + ((u >> 16) & 1u)) >> 16;   // RNE
    return (unsigned short)r;
}

// ---------------------------------------------------------------- K0: convert
__global__ __launch_bounds__(256)
void k_convert(const float* __restrict__ pe, const float* __restrict__ per,
               unsigned short* __restrict__ abf, unsigned short* __restrict__ rbf,
               unsigned short* __restrict__ rbf8, float* __restrict__ rnorm)
{
    const int AROWS = L_DIM * M_PAD;            // 43776
    const int BROWS = L_DIM * N_PAD;            // 5376
    int wid = (blockIdx.x * 256 + threadIdx.x) >> 6;
    int lane = threadIdx.x & 63;
    const ushort4 z4 = {0, 0, 0, 0};
    if (wid < AROWS) {
        int l = wid / M_PAD, r = wid - l * M_PAD;
        unsigned short* dst = abf + (size_t)wid * D_DIM;
        if (r < M_TOT) {
            const float4* src = (const float4*)(pe + ((size_t)l * M_TOT + r) * D_DIM);
            float ss = 0.f;
            #pragma unroll
            for (int it = 0; it < 3; ++it) {
                int idx = it * 64 + lane;
                if (idx < 160) {
                    float4 v = src[idx];
                    ss += v.x * v.x + v.y * v.y + v.z * v.z + v.w * v.w;
                    ushort4 o;
                    o.x = f2bf(v.x); o.y = f2bf(v.y); o.z = f2bf(v.z); o.w = f2bf(v.w);
                    *(ushort4*)(dst + idx * 4) = o;
                }
            }
            #pragma unroll
            for (int m = 32; m; m >>= 1) ss += __shfl_xor(ss, m);
            if (lane == 0) rnorm[l * M_TOT + r] = rsqrtf(ss);
        } else {
            #pragma unroll
            for (int it = 0; it < 3; ++it) {
                int idx = it * 64 + lane;
                if (idx < 160) *(ushort4*)(dst + idx * 4) = z4;
            }
        }
    } else if (wid < AROWS + BROWS) {
        int w2 = wid - AROWS;
        int l = w2 / N_PAD, r = w2 - l * N_PAD;   // r < 1792 always real
        unsigned short* dst = rbf + (size_t)w2 * D_DIM;
        const float4* src = (const float4*)(per + ((size_t)l * R_DIM + r) * D_DIM);
        #pragma unroll
        for (int it = 0; it < 3; ++it) {
            int idx = it * 64 + lane;
            if (idx < 160) {
                float4 v = src[idx];
                ushort4 o;
                o.x = f2bf(v.x); o.y = f2bf(v.y); o.z = f2bf(v.z); o.w = f2bf(v.w);
                *(ushort4*)(dst + idx * 4) = o;
            }
        }
    } else {
        int w3 = wid - AROWS - BROWS;             // 0..47
        int l = w3 >> 4, r = w3 & 15;
        unsigned short* dst = rbf8 + (size_t)(l * 16 + r) * D_DIM;
        if (r < 8) {
            const float4* src = (const float4*)(per + ((size_t)l * R_DIM + 1792 + r) * D_DIM);
            #pragma unroll
            for (int it = 0; it < 3; ++it) {
                int idx = it * 64 + lane;
                if (idx < 160) {
                    float4 v = src[idx];
                    ushort4 o;
                    o.x = f2bf(v.x); o.y = f2bf(v.y); o.z = f2bf(v.z); o.w = f2bf(v.w);
                    *(ushort4*)(dst + idx * 4) = o;
                }
            }
        } else {
            #pragma unroll
            for (int it = 0; it < 3; ++it) {
                int idx = it * 64 + lane;
                if (idx < 160) *(ushort4*)(dst + idx * 4) = z4;
            }
        }
    }
}

// ----------------------------------- K1: 256^2 4-phase bf16 GEMM + fused rowmax
// (Round-6 proven schedule; NT=7 so all 1792 cols are real -> no masking.
//  launch_bounds(512,1): LDS caps at 1 block/CU anyway; lift the VGPR-128 cap.)
#define MFMA(A, B, C) __builtin_amdgcn_mfma_f32_16x16x32_bf16((A), (B), (C), 0, 0, 0)
#define GLL(SRC, DSTOFF)                                                     \
    __builtin_amdgcn_global_load_lds(                                        \
        (const __attribute__((address_space(1))) void*)(SRC),               \
        (__attribute__((address_space(3))) void*)(lds + (DSTOFF)), 16, 0, 0)

#define PHASE_TAIL(NJB, STG0, STG1, VMSTR)                                   \
    {                                                                        \
        bf16x8 b00 = *(const bf16x8*)(lds + bB + (brow0 + (NJB) * 16) * 64 + sw0);     \
        bf16x8 b01 = *(const bf16x8*)(lds + bB + (brow0 + (NJB) * 16) * 64 + sw1);     \
        bf16x8 b10 = *(const bf16x8*)(lds + bB + (brow0 + (NJB + 1) * 16) * 64 + sw0); \
        bf16x8 b11 = *(const bf16x8*)(lds + bB + (brow0 + (NJB + 1) * 16) * 64 + sw1); \
        STG0; STG1;                                                          \
        asm volatile("s_waitcnt " VMSTR ::: "memory");                       \
        __builtin_amdgcn_s_barrier();                                        \
        __builtin_amdgcn_s_setprio(1);                                       \
        _Pragma("unroll")                                                    \
        for (int mi = 0; mi < 4; ++mi) {                                     \
            acc[mi][NJB]     = MFMA(a[mi][0], b00, acc[mi][NJB]);            \
            acc[mi][NJB]     = MFMA(a[mi][1], b01, acc[mi][NJB]);            \
            acc[mi][NJB + 1] = MFMA(a[mi][0], b10, acc[mi][NJB + 1]);        \
            acc[mi][NJB + 1] = MFMA(a[mi][1], b11, acc[mi][NJB + 1]);        \
        }                                                                    \
        __builtin_amdgcn_s_setprio(0);                                       \
    }

__global__ __launch_bounds__(512, 1)
void k_gemm_max(const unsigned short* __restrict__ abf,
                const unsigned short* __restrict__ rbf,
                float* __restrict__ pmax)
{
    __shared__ unsigned short lds[65536];   // A: [0,32768) 2 bufs; B: [32768,65536)
    __shared__ float red[2][256];

    // bijective XCD-chunked swizzle: 1197 = 5*150 + 3*149
    int bid = blockIdx.x;
    int xcd = bid & 7, idx = bid >> 3;
    int v = (xcd < 5 ? xcd * 150 : 750 + (xcd - 5) * 149) + idx;
    int l = v / (MT * NT);
    int rem = v - l * (MT * NT);
    int mt = rem / NT;
    int nt = rem - mt * NT;

    int tid = threadIdx.x;
    int wid = tid >> 6, lane = tid & 63;
    int wm = wid >> 1;                      // 0..3 -> rows wm*64
    int wn = wid & 1;                       // 0..1 -> cols wn*128
    int lane15 = lane & 15, lg = lane >> 4;
    int sA = lane15 & 7;
    int sw0 = ((lg) ^ sA) << 3;             // ks=0: swizzled col-chunk, in shorts
    int sw1 = ((4 + lg) ^ sA) << 3;         // ks=1
    int arow0 = wm * 64 + lane15;
    int brow0 = wn * 128 + lane15;

    // staging source (pre-swizzled global col so linear LDS dest ends up swizzled)
    int rowc = lane >> 3;
    int scol = ((lane & 7) ^ rowc) << 3;
    const unsigned short* gA = abf + (size_t)(l * M_PAD + mt * 256) * D_DIM;
    const unsigned short* gB = rbf + (size_t)(l * N_PAD + nt * 256) * D_DIM;
    int chA0 = wid, chA1 = 8 + wid, chA2 = 16 + wid, chA3 = 24 + wid;
    int chB0 = (wid < 4) ? (0 + wid) : (12 + wid);
    int chB1 = (wid < 4) ? (4 + wid) : (16 + wid);
    int chB2 = (wid < 4) ? (8 + wid) : (20 + wid);
    int chB3 = (wid < 4) ? (12 + wid) : (24 + wid);
    const unsigned short* pA0 = gA + (size_t)(chA0 * 8 + rowc) * D_DIM + scol;
    const unsigned short* pA1 = gA + (size_t)(chA1 * 8 + rowc) * D_DIM + scol;
    const unsigned short* pA2 = gA + (size_t)(chA2 * 8 + rowc) * D_DIM + scol;
    const unsigned short* pA3 = gA + (size_t)(chA3 * 8 + rowc) * D_DIM + scol;
    const unsigned short* pB0 = gB + (size_t)(chB0 * 8 + rowc) * D_DIM + scol;
    const unsigned short* pB1 = gB + (size_t)(chB1 * 8 + rowc) * D_DIM + scol;
    const unsigned short* pB2 = gB + (size_t)(chB2 * 8 + rowc) * D_DIM + scol;
    const unsigned short* pB3 = gB + (size_t)(chB3 * 8 + rowc) * D_DIM + scol;

    f32x4 acc[4][8];
    #pragma unroll
    for (int mi = 0; mi < 4; ++mi)
        #pragma unroll
        for (int nj = 0; nj < 8; ++nj)
            acc[mi][nj] = f32x4{0.f, 0.f, 0.f, 0.f};

    // prologue: stage K-tile 0 into buf0; need A0..A3 + Bq0 before phase 0
    GLL(pA0, chA0 * 512); GLL(pA1, chA1 * 512);
    GLL(pA2, chA2 * 512); GLL(pA3, chA3 * 512);
    GLL(pB0, 32768 + chB0 * 512); GLL(pB1, 32768 + chB1 * 512);
    GLL(pB2, 32768 + chB2 * 512); GLL(pB3, 32768 + chB3 * 512);
    asm volatile("s_waitcnt vmcnt(3)" ::: "memory");
    __builtin_amdgcn_s_barrier();

    int buf = 0;
    for (int kt = 0; kt < KT; ++kt) {
        int ob = buf ^ 1;
        int aB = buf * 16384;
        int bB = 32768 + buf * 16384;
        int oaB = ob * 16384;
        int obB = 32768 + ob * 16384;
        int koff = (kt + 1 < KT ? kt + 1 : KT - 1) * 64;   // kt=9 restages (dummy)

        // phase 0: read A-all + B quadrant 0; stage A0',A1'
        bf16x8 a[4][2];
        #pragma unroll
        for (int mi = 0; mi < 4; ++mi) {
            a[mi][0] = *(const bf16x8*)(lds + aB + (arow0 + mi * 16) * 64 + sw0);
            a[mi][1] = *(const bf16x8*)(lds + aB + (arow0 + mi * 16) * 64 + sw1);
        }
        PHASE_TAIL(0, GLL(pA0 + koff, oaB + chA0 * 512),
                      GLL(pA1 + koff, oaB + chA1 * 512), "vmcnt(4)")
        // phase 1: B quadrant 1; stage A2',A3'
        PHASE_TAIL(2, GLL(pA2 + koff, oaB + chA2 * 512),
                      GLL(pA3 + koff, oaB + chA3 * 512), "vmcnt(5)")
        // phase 2: B quadrant 2; stage B0',B1'
        PHASE_TAIL(4, GLL(pB0 + koff, obB + chB0 * 512),
                      GLL(pB1 + koff, obB + chB1 * 512), "vmcnt(6)")
        // phase 3: B quadrant 3; stage B2',B3'
        PHASE_TAIL(6, GLL(pB2 + koff, obB + chB2 * 512),
                      GLL(pB3 + koff, obB + chB3 * 512), "vmcnt(3)")
        buf = ob;
    }

    __syncthreads();

    // fused epilogue: rowmax over the block's 256 cols (all real).
    // C/D layout: col = lane&15, row = (lane>>4)*4 + reg  [m89-verified]
    #pragma unroll
    for (int mi = 0; mi < 4; ++mi) {
        float t[4] = {-__builtin_inff(), -__builtin_inff(),
                      -__builtin_inff(), -__builtin_inff()};
        #pragma unroll
        for (int nj = 0; nj < 8; ++nj) {
            #pragma unroll
            for (int r = 0; r < 4; ++r) t[r] = fmaxf(t[r], acc[mi][nj][r]);
        }
        #pragma unroll
        for (int m = 1; m <= 8; m <<= 1) {
            #pragma unroll
            for (int r = 0; r < 4; ++r) t[r] = fmaxf(t[r], __shfl_xor(t[r], m));
        }
        if (lane15 == 0) {
            int rb = wm * 64 + mi * 16 + lg * 4;
            #pragma unroll
            for (int r = 0; r < 4; ++r) red[wn][rb + r] = t[r];
        }
    }
    __syncthreads();
    if (tid < 256) {
        float vmx = fmaxf(red[0][tid], red[1][tid]);
        pmax[((size_t)l * NT + nt) * M_PAD + mt * 256 + tid] = vmx;
    }
}

// ------------- K2: remainder refs 1792..1799 -> rmax8[l][row] (MFMA, 16-row tiles)
// LDS rows padded to LPAD shorts: bank = lane15*4 mod 32 -> 2-way (free).
__global__ __launch_bounds__(256)
void k_rem(const unsigned short* __restrict__ abf,
           const unsigned short* __restrict__ rbf8,
           float* __restrict__ rmax8)
{
    __shared__ unsigned short ldsb[16 * LPAD];     // ~20.7KB, one l per block
    int bid = blockIdx.x;                          // 675 blocks, 64 rows each
    int rflat0 = bid * 64;
    int l = rflat0 / M_TOT;                        // blocks never cross l (14400%64==0)
    int tid = threadIdx.x;

    {   // stage this l's 16 ref rows (8 real + 8 zero) into padded LDS
        const unsigned* src = (const unsigned*)(rbf8 + (size_t)l * 16 * D_DIM);
        #pragma unroll
        for (int it = 0; it < 20; ++it) {
            int i = it * 256 + tid;                // 0..5119
            int r = i / 320, c = i - r * 320;
            *(unsigned*)(ldsb + r * LPAD + c * 2) = src[i];
        }
    }
    __syncthreads();

    int w = tid >> 6, lane = tid & 63;
    int lane15 = lane & 15, lg = lane >> 4;
    int rl = (rflat0 - l * M_TOT) + w * 16;        // wave's 16-row base within l

    const unsigned short* arow = abf + (size_t)(l * M_PAD + rl + lane15) * D_DIM;
    const unsigned short* brow = ldsb + (size_t)lane15 * LPAD;

    f32x4 acc = f32x4{0.f, 0.f, 0.f, 0.f};
    for (int kk = 0; kk < D_DIM; kk += 32) {
        bf16x8 a = *(const bf16x8*)(arow + kk + lg * 8);
        bf16x8 b = *(const bf16x8*)(brow + kk + lg * 8);
        acc = MFMA(a, b, acc);
    }

    // C/D: col = lane15 (ref idx; >=8 are zero rows -> mask), row = lg*4+reg
    float t[4];
    #pragma unroll
    for (int r = 0; r < 4; ++r)
        t[r] = (lane15 < 8) ? acc[r] : -__builtin_inff();
    #pragma unroll
    for (int m = 1; m <= 8; m <<= 1) {
        #pragma unroll
        for (int r = 0; r < 4; ++r) t[r] = fmaxf(t[r], __shfl_xor(t[r], m));
    }
    if (lane15 == 0) {
        #pragma unroll
        for (int r = 0; r < 4; ++r)
            rmax8[(size_t)l * M_TOT + rl + lg * 4 + r] = t[r];
    }
}

// --------------------- K3: small net + fused combine (512 thr)
__device__ __forceinline__ float block_sum8(float v, volatile float* scratch) {
    #pragma unroll
    for (int m = 32; m; m >>= 1) v += __shfl_xor(v, m);
    int w = threadIdx.x >> 6;
    __syncthreads();
    if ((threadIdx.x & 63) == 0) scratch[w] = v;
    __syncthreads();
    float r = 0.f;
    #pragma unroll
    for (int i = 0; i < 8; ++i) r += scratch[i];
    return r;
}
__device__ __forceinline__ float block_max8(float v, volatile float* scratch) {
    #pragma unroll
    for (int m = 32; m; m >>= 1) v = fmaxf(v, __shfl_xor(v, m));
    int w = threadIdx.x >> 6;
    __syncthreads();
    if ((threadIdx.x & 63) == 0) scratch[w] = v;
    __syncthreads();
    float r = scratch[0];
    #pragma unroll
    for (int i = 1; i < 8; ++i) r = fmaxf(r, scratch[i]);
    return r;
}

__global__ __launch_bounds__(512)
void k_small(const float* __restrict__ ie, const float* __restrict__ te,
             const float* __restrict__ ier,
             const float* __restrict__ a_w1, const float* __restrict__ a_w2,
             const float* __restrict__ r_w1, const float* __restrict__ r_b1,
             const float* __restrict__ r_g2, const float* __restrict__ r_be2,
             const float* __restrict__ r_w2, const float* __restrict__ r_b2,
             const float* __restrict__ r_g3, const float* __restrict__ r_be3,
             const float* __restrict__ r_w3, const float* __restrict__ r_b3,
             const float* __restrict__ h_w1, const float* __restrict__ h_b1,
             const float* __restrict__ h_g2, const float* __restrict__ h_be2,
             const float* __restrict__ h_w2, const float* __restrict__ h_b2,
             const float* __restrict__ h_g3, const float* __restrict__ h_be3,
             const float* __restrict__ h_w3, const float* __restrict__ h_b3,
             const float* __restrict__ pmax, const float* __restrict__ rmax8,
             const float* __restrict__ rnorm,
             float* __restrict__ heat, float* __restrict__ out_score)
{
    int b = blockIdx.x, tid = threadIdx.x;
    __shared__ float x[D_DIM];
    __shared__ float h1[160];
    __shared__ float dif[D_DIM];
    __shared__ float z1[128];
    __shared__ float z2[64];
    __shared__ float hol[P_DIM];
    __shared__ float rcp[P_DIM];
    __shared__ float scratch[8];

    for (int i = tid; i < D_DIM; i += 512) x[i] = ie[b * D_DIM + i];
    __syncthreads();

    float ss = 0.f, d0 = 0.f, d1 = 0.f;
    for (int i = tid; i < D_DIM; i += 512) {
        float v = x[i];
        ss += v * v;
        d0 += v * te[i];
        d1 += v * te[D_DIM + i];
    }
    float ssum = block_sum8(ss, scratch);
    float dd0 = block_sum8(d0, scratch);
    float dd1 = block_sum8(d1, scratch);
    float tscore = 1.f / (1.f + expf(100.f * rsqrtf(ssum) * (dd0 - dd1)));

    for (int o = tid; o < 160; o += 512) {
        const float* w = a_w1 + (size_t)o * D_DIM;
        float s0 = 0, s1 = 0, s2 = 0, s3 = 0;
        for (int d = 0; d < D_DIM; d += 4) {
            s0 += x[d] * w[d]; s1 += x[d + 1] * w[d + 1];
            s2 += x[d + 2] * w[d + 2]; s3 += x[d + 3] * w[d + 3];
        }
        h1[o] = fmaxf((s0 + s1) + (s2 + s3), 0.f);
    }
    __syncthreads();
    for (int d = tid; d < D_DIM; d += 512) {
        const float* w = a_w2 + (size_t)d * 160;
        float s0 = 0, s1 = 0, s2 = 0, s3 = 0;
        for (int o = 0; o < 160; o += 4) {
            s0 += h1[o] * w[o]; s1 += h1[o + 1] * w[o + 1];
            s2 += h1[o + 2] * w[o + 2]; s3 += h1[o + 3] * w[o + 3];
        }
        dif[d] = ier[d] - fmaxf((s0 + s1) + (s2 + s3), 0.f);
    }
    __syncthreads();

    for (int o = tid; o < 128; o += 512) {
        const float* w = r_w1 + (size_t)o * D_DIM;
        float s0 = 0, s1 = 0, s2 = 0, s3 = 0;
        for (int d = 0; d < D_DIM; d += 4) {
            s0 += dif[d] * w[d]; s1 += dif[d + 1] * w[d + 1];
            s2 += dif[d + 2] * w[d + 2]; s3 += dif[d + 3] * w[d + 3];
        }
        float s = (s0 + s1) + (s2 + s3) + r_b1[o];
        z1[o] = fmaxf(s, 0.f) * (r_g2[o] * BNSCALE) + r_be2[o];
    }
    __syncthreads();
    for (int o = tid; o < 64; o += 512) {
        const float* w = r_w2 + (size_t)o * 128;
        float s = r_b2[o];
        for (int d = 0; d < 128; ++d) s += z1[d] * w[d];
        z2[o] = fmaxf(s, 0.f) * (r_g3[o] * BNSCALE) + r_be3[o];
    }
    __syncthreads();
    float sp = (tid < 64) ? z2[tid] * r_w3[tid] : 0.f;
    float irs = 1.f / (1.f + expf(-(block_sum8(sp, scratch) + r_b3[0])));

    float fgp = -__builtin_inff();
    float base = tscore + irs;
    for (int p = tid; p < P_DIM; p += 512) {
        int r = b * P_DIM + p;
        float s = 0.f;
        #pragma unroll
        for (int l = 0; l < L_DIM; ++l) {
            float m = rmax8[(size_t)l * M_TOT + r];
            #pragma unroll
            for (int t = 0; t < NT; ++t)
                m = fmaxf(m, pmax[((size_t)l * NT + t) * M_PAD + r]);
            s += m * rnorm[l * M_TOT + r];
        }
        float pv = (3.0f - s) / 6.0f;
        fgp = fmaxf(fgp, pv);
        float h = base + pv;
        hol[p] = h;
        rcp[p] = 1.f / h;
    }
    float fg = block_max8(fgp, scratch);

    for (int o = tid; o < 128; o += 512) {
        const float* w = h_w1 + (size_t)o * P_DIM;
        float s = h_b1[o];
        for (int d = 0; d < P_DIM; ++d) s += hol[d] * w[d];
        z1[o] = fmaxf(s, 0.f) * (h_g2[o] * BNSCALE) + h_be2[o];
    }
    __syncthreads();
    for (int o = tid; o < 64; o += 512) {
        const float* w = h_w2 + (size_t)o * 128;
        float s = h_b2[o];
        for (int d = 0; d < 128; ++d) s += z1[d] * w[d];
        z2[o] = fmaxf(s, 0.f) * (h_g3[o] * BNSCALE) + h_be3[o];
    }
    __syncthreads();
    float sp2 = (tid < 64) ? z2[tid] * h_w3[tid] : 0.f;
    float hl_in = block_sum8(sp2, scratch) + h_b3[0];
    if (tid == 0) {
        float hl = 1.f / (1.f + expf(-hl_in));
        out_score[b] = (hl + fg) * 0.5f;
    }

    if (tid < 256) {
        int r = tid >> 4, c = tid & 15;
        float s = 0.f, cnt = 0.f;
        #pragma unroll
        for (int di = -1; di <= 0; ++di) {
            int i = r + di;
            if (i < 0 || i > 14) continue;
            #pragma unroll
            for (int dj = -1; dj <= 0; ++dj) {
                int j = c + dj;
                if (j < 0 || j > 14) continue;
                s += rcp[i * 15 + j];
                cnt += 1.f;
            }
        }
        heat[b * 256 + tid] = cnt / s;
    }
}

// ------------------------------------------------------------- K4: resize
__global__ __launch_bounds__(256)
void k_resize(const float* __restrict__ heat, float* __restrict__ outh)
{
    int b = blockIdx.x >> 3, sub = blockIdx.x & 7;
    __shared__ float h[256];
    if (threadIdx.x < 256) h[threadIdx.x] = heat[b * 256 + threadIdx.x];
    __syncthreads();
    int base = sub * 30 * S_DIM;
    for (int q = threadIdx.x; q < 30 * S_DIM; q += 256) {
        int px = base + q;
        int y = px / S_DIM, xc = px - y * S_DIM;
        float sy = fminf(fmaxf((y - 7) * (1.0f / 15.0f), 0.f), 15.f);
        float sx = fminf(fmaxf((xc - 7) * (1.0f / 15.0f), 0.f), 15.f);
        int y0 = (int)sy, x0 = (int)sx;
        int y1 = min(y0 + 1, 15), x1 = min(x0 + 1, 15);
        float fy = sy - (float)y0, fx = sx - (float)x0;
        float v00 = h[y0 * 16 + x0], v01 = h[y0 * 16 + x1];
        float v10 = h[y1 * 16 + x0], v11 = h[y1 * 16 + x1];
        float v = (1.f - fy) * ((1.f - fx) * v00 + fx * v01)
                + fy * ((1.f - fx) * v10 + fx * v11);
        outh[(size_t)b * (S_DIM * S_DIM) + px] = v;
    }
}

// ---------------------------------------------------------------- launcher
extern "C" void kernel_launch(void* const* d_in, const int* in_sizes, int n_in,
                              void* d_out, int out_size, void* d_ws, size_t ws_size,
                              hipStream_t stream)
{
    (void)in_sizes; (void)n_in; (void)out_size; (void)ws_size;
    const float* image_embeds = (const float*)d_in[1];
    const float* patch_embeds = (const float*)d_in[2];
    const float* text_embeds  = (const float*)d_in[3];
    const float* ier          = (const float*)d_in[4];
    const float* per          = (const float*)d_in[5];
    const float* a_w1 = (const float*)d_in[6];
    const float* a_w2 = (const float*)d_in[7];
    const float* r_w1 = (const float*)d_in[8];
    const float* r_b1 = (const float*)d_in[9];
    const float* r_g2 = (const float*)d_in[10];
    const float* r_be2 = (const float*)d_in[11];
    const float* r_w2 = (const float*)d_in[12];
    const float* r_b2 = (const float*)d_in[13];
    const float* r_g3 = (const float*)d_in[14];
    const float* r_be3 = (const float*)d_in[15];
    const float* r_w3 = (const float*)d_in[16];
    const float* r_b3 = (const float*)d_in[17];
    const float* h_w1 = (const float*)d_in[18];
    const float* h_b1 = (const float*)d_in[19];
    const float* h_g2 = (const float*)d_in[20];
    const float* h_be2 = (const float*)d_in[21];
    const float* h_w2 = (const float*)d_in[22];
    const float* h_b2 = (const float*)d_in[23];
    const float* h_g3 = (const float*)d_in[24];
    const float* h_be3 = (const float*)d_in[25];
    const float* h_w3 = (const float*)d_in[26];
    const float* h_b3 = (const float*)d_in[27];

    char* ws = (char*)d_ws;
    size_t off = 0;
    auto take = [&](size_t bytes) -> void* {
        void* p = ws + off;
        off += (bytes + 255) & ~(size_t)255;
        return p;
    };
    float* rnorm = (float*)take((size_t)L_DIM * M_TOT * 4);            // 173 KB
    float* pmax  = (float*)take((size_t)L_DIM * NT * M_PAD * 4);       // 1.2 MB
    float* rmax8 = (float*)take((size_t)L_DIM * M_TOT * 4);            // 173 KB
    float* heat  = (float*)take((size_t)B_DIM * 256 * 4);              // 64 KB
    unsigned short* abf  = (unsigned short*)take((size_t)L_DIM * M_PAD * D_DIM * 2); // 56.0 MB
    unsigned short* rbf  = (unsigned short*)take((size_t)L_DIM * N_PAD * D_DIM * 2); //  6.9 MB
    unsigned short* rbf8 = (unsigned short*)take((size_t)L_DIM * 16 * D_DIM * 2);    //  61 KB

    float* out_f = (float*)d_out;  // [64] final_score || [64*240*240] hmap, f32

    k_convert<<<dim3((L_DIM * M_PAD + L_DIM * N_PAD + L_DIM * 16) / 4), dim3(256), 0, stream>>>(
        patch_embeds, per, abf, rbf, rbf8, rnorm);
    k_rem<<<dim3(L_DIM * M_TOT / 64), dim3(256), 0, stream>>>(abf, rbf8, rmax8);
    k_gemm_max<<<dim3(L_DIM * MT * NT), dim3(512), 0, stream>>>(abf, rbf, pmax);
    k_small<<<dim3(B_DIM), dim3(512), 0, stream>>>(image_embeds, text_embeds, ier,
        a_w1, a_w2, r_w1, r_b1, r_g2, r_be2, r_w2, r_b2, r_g3, r_be3, r_w3, r_b3,
        h_w1, h_b1, h_g2, h_be2, h_w2, h_b2, h_g3, h_be3, h_w3, h_b3,
        pmax, rmax8, rnorm, heat, out_f);
    k_resize<<<dim3(B_DIM * 8), dim3(256), 0, stream>>>(heat, out_f + B_DIM);
}